// Round 14
// baseline (173.666 us; speedup 1.0000x reference)
//
#include <hip/hip_runtime.h>
#include <stdint.h>

typedef unsigned short u16;
typedef unsigned int u32;
typedef __attribute__((ext_vector_type(8))) short short8;
typedef __attribute__((ext_vector_type(4))) float f32x4;
typedef __attribute__((ext_vector_type(8))) unsigned short u16x8;
typedef __attribute__((ext_vector_type(4))) float float4_t;

__device__ __forceinline__ float b2f(u16 u) { return __uint_as_float(((u32)u) << 16); }
__device__ __forceinline__ u16 f2b(float f) {
  u32 u = __float_as_uint(f);
  u += 0x7fffu + ((u >> 16) & 1u);
  return (u16)(u >> 16);
}

typedef const __attribute__((address_space(1))) void* gas_t;
typedef __attribute__((address_space(3))) void* las_t;
__device__ __forceinline__ void gl_lds16(const void* g, void* l) {
  __builtin_amdgcn_global_load_lds((gas_t)(uintptr_t)g, (las_t)(u32)(uintptr_t)l, 16, 0, 0);
}
__device__ __forceinline__ void barrier_pin() {
  __builtin_amdgcn_sched_barrier(0);
  __builtin_amdgcn_s_barrier();
  __builtin_amdgcn_sched_barrier(0);
}
__device__ __forceinline__ void lgkm0_pin() {
  asm volatile("s_waitcnt lgkmcnt(0)" ::: "memory");
  __builtin_amdgcn_sched_barrier(0);  // rule #18
}

// ---------------- fp32 -> bf16 convert (vectorized) ----------------
__global__ __launch_bounds__(256) void cvt_f2b_kernel(const float* __restrict__ src,
                                                      u16* __restrict__ dst, long n) {
  long i = ((long)blockIdx.x * 256 + threadIdx.x) * 8;
  if (i >= n) return;
  float4_t v0 = *(const float4_t*)(src + i);
  float4_t v1 = *(const float4_t*)(src + i + 4);
  u16x8 o;
#pragma unroll
  for (int j = 0; j < 4; ++j) { o[j] = f2b(v0[j]); o[4 + j] = f2b(v1[j]); }
  *(u16x8*)(dst + i) = o;
}

// ------------- fp32 [R][C] -> bf16 [C][R] transpose+convert -------------
__global__ __launch_bounds__(256) void tr_cvt(const float* __restrict__ src,
                                              u16* __restrict__ dst, int R, int C) {
  __shared__ float t[32][33];
  const int bx = blockIdx.x * 32;
  const int by = blockIdx.y * 32;
  const int tx = threadIdx.x & 31, ty = threadIdx.x >> 5;
#pragma unroll
  for (int i = 0; i < 32; i += 8)
    t[ty + i][tx] = src[(long)(by + ty + i) * C + bx + tx];
  __syncthreads();
#pragma unroll
  for (int i = 0; i < 32; i += 8)
    dst[(long)(bx + ty + i) * R + by + tx] = f2b(t[tx][ty + i]);
}

// ------------- V slice of qkv [B][N][1536] -> vt [B][512][2048] (bf16) -------------
__global__ __launch_bounds__(256) void tr_v(const u16* __restrict__ qkv, u16* __restrict__ vt) {
  __shared__ u16 t[32][33];
  const int b = blockIdx.z;
  const int r0 = blockIdx.x * 32;
  const int d0 = blockIdx.y * 32;
  const int tx = threadIdx.x & 31, ty = threadIdx.x >> 5;
#pragma unroll
  for (int i = 0; i < 32; i += 8)
    t[ty + i][tx] = qkv[((long)b * 2048 + r0 + ty + i) * 1536 + 1024 + d0 + tx];
  __syncthreads();
#pragma unroll
  for (int i = 0; i < 32; i += 8)
    vt[((long)b * 512 + d0 + ty + i) * 2048 + r0 + tx] = t[tx][ty + i];
}

// ============ 128x128 BK=32 TRIPLE-buffer depth-2 BT-GEMM, 3 blocks/CU ============
// C[M][N] = A[M][K] @ Bt[N][K]^T. BM=BN=128, BK=32. 512 thr = 8 waves
// (wr=wid>>2: 64-row half; wc=wid&3: 32-col strip; per-wave C = 64x32 — the
// empirically fastest geometry, r9). LDS = 3buf x (A 8KB + B 8KB) = 48KB ->
// 3 blocks/CU (24 waves). Composition of the only two proven levers:
//   occupancy (r8->r9) + depth-2 counted vmcnt (r1->r2, ledger verified then):
// Phase T (buf = T%3):
//   stage(T+2) -> buf[(T+2)%3]   // WAR: that buf was read in phase T-1; its
//                                // readers' lgkm0 preceded T-1's end barrier
//   6 ds_read of tile T          // RAW: stage(T) drained end of phase T-2
//   lgkm0 ; setprio(1) ; 8 MFMA ; setprio(0)
//   vmcnt(2)                     // only this phase's stage (2 loads) in flight
//                                // -> stage(T+1), issued a FULL phase ago, landed
//   BAR
// (tail: T+2>=nT -> no stage; drain vmcnt(0) once at T==nT-2.)
// Per-thread loads/stage = 2 (A 1 + B 1; 128x32 tile = 512thr x 16B exactly).
//
// k-slot swizzle for 64B rows (r13-corrected key, both sides): b128 bank-quad
// = 4*(row&1) + slot, so XOR key f(row) = (row>>1)&3. Staging thread t:
// dest row t>>2, dest slot t&3 (byte t*16, linear ✓), src slot (t&3)^((t>>3)&3).
// Reads: slot = lg ^ ((lr>>1)&3) (frag rows = 16k + lr) -> 8-lane groups
// enumerate all 8 quads (verified by enumeration) -> conflict-free.
// XCD bijective remap (all grids %8==0).
//
// EXP_EPI: p=exp(alpha*s) epilogue (QK^T). ROWSUM_DIV: l=rowsum(A) via gated
// ones-MFMA (wc==0 waves, +4 MFMA/phase), O/l epilogue (PV; r11-verified).
template <bool OUT_F32, bool BIAS, bool RES, bool EXP_EPI, bool ROWSUM_DIV>
__global__ __launch_bounds__(512, 4)
void gemm128t(const u16* __restrict__ A, const u16* __restrict__ Bt, void* __restrict__ Cv,
              const float* __restrict__ bias, const float* __restrict__ res,
              int K, int lda, int ldb, int ldc,
              long aStride, long bStride, long cStride, float alpha) {
  __shared__ u16 As[3][128 * 32];
  __shared__ u16 Bs[3][128 * 32];
  __shared__ float lsum[ROWSUM_DIV ? 128 : 1];
  const int tid = threadIdx.x;
  const int wid = tid >> 6, lane = tid & 63;
  const int wr = wid >> 2, wc = wid & 3;
  const int lr = lane & 15, lg = lane >> 4;

  const int gx = gridDim.x, gy = gridDim.y;
  int id = (blockIdx.z * gy + blockIdx.y) * gx + blockIdx.x;
  const int nwg = gx * gy * gridDim.z;
  id = (id & 7) * (nwg >> 3) + (id >> 3);
  const int bxi = id % gx;
  const int t2 = id / gx;
  const int byi = t2 % gy;
  const long z = t2 / gy;

  A += z * aStride;
  Bt += z * bStride;
  const int by = byi * 128;
  const int bx = bxi * 128;

  f32x4 acc[4][2] = {};
  f32x4 acc_l[4] = {};  // ROWSUM_DIV only
  short8 ah[4], bh[2];
  short8 ones;
#pragma unroll
  for (int j = 0; j < 8; ++j) ones[j] = (short)0x3F80;  // bf16 1.0

  const int th_row = tid >> 2;                                // 0..127
  const int slot_lin = (tid & 3) * 8;                         // dest slot (elems)
  const int slot_src = (((tid & 3) ^ ((tid >> 3) & 3)) * 8);  // f(row)=(row>>1)&3
  const int nT = K >> 5;
  const int sxk = (lr >> 1) & 3;                              // read key

  const u16* Ag = A + (long)(by + th_row) * lda + slot_src;
  const u16* Bg = Bt + (long)(bx + th_row) * ldb + slot_src;
  const int dL = th_row * 32 + slot_lin;

  auto stage = [&](int kt) {
    int bb = kt % 3;
    const long ko = (long)kt * 32;
    gl_lds16(Ag + ko, &As[bb][dL]);
    gl_lds16(Bg + ko, &Bs[bb][dL]);
  };

  // -------- prologue: tiles 0,1 into bufs 0,1; wait tile 0 (all but newest 2) --------
  stage(0);
  stage(1);
  asm volatile("s_waitcnt vmcnt(2)" ::: "memory");
  barrier_pin();

  // -------- main loop: one phase per K-tile, depth-2 prefetch --------
  for (int T = 0; T < nT; ++T) {
    const int bb = T % 3;
    if (T + 2 < nT) stage(T + 2);
#pragma unroll
    for (int mi = 0; mi < 4; ++mi)
      ah[mi] = *(const short8*)&As[bb][(wr * 64 + mi * 16 + lr) * 32 + ((lg ^ sxk) * 8)];
#pragma unroll
    for (int n = 0; n < 2; ++n)
      bh[n] = *(const short8*)&Bs[bb][(wc * 32 + n * 16 + lr) * 32 + ((lg ^ sxk) * 8)];
    lgkm0_pin();
    __builtin_amdgcn_s_setprio(1);
#pragma unroll
    for (int mi = 0; mi < 4; ++mi)
#pragma unroll
      for (int n = 0; n < 2; ++n)
        acc[mi][n] = __builtin_amdgcn_mfma_f32_16x16x32_bf16(
            ah[mi], bh[n], acc[mi][n], 0, 0, 0);
    if constexpr (ROWSUM_DIV) {
      if (wc == 0) {
#pragma unroll
        for (int mi = 0; mi < 4; ++mi)
          acc_l[mi] = __builtin_amdgcn_mfma_f32_16x16x32_bf16(
              ah[mi], ones, acc_l[mi], 0, 0, 0);
      }
    }
    __builtin_amdgcn_s_setprio(0);
    if (T + 2 < nT)      asm volatile("s_waitcnt vmcnt(2)" ::: "memory");
    else if (T + 1 < nT) asm volatile("s_waitcnt vmcnt(0)" ::: "memory");
    barrier_pin();
  }

  // -------- epilogue: row = by+wr*64+mi*16+lg*4+j ; col = bx+wc*32+ni*16+lr --------
  if constexpr (ROWSUM_DIV) {
    if (wc == 0 && lr == 0) {
#pragma unroll
      for (int mi = 0; mi < 4; ++mi)
#pragma unroll
        for (int j = 0; j < 4; ++j)
          lsum[wr * 64 + mi * 16 + lg * 4 + j] = acc_l[mi][j];
    }
    __syncthreads();
  }

  if constexpr (EXP_EPI) {
    u16* C = (u16*)Cv + z * cStride;
#pragma unroll
    for (int mi = 0; mi < 4; ++mi)
#pragma unroll
      for (int ni = 0; ni < 2; ++ni)
#pragma unroll
        for (int j = 0; j < 4; ++j) {
          const long row = by + wr * 64 + mi * 16 + lg * 4 + j;
          const int col = bx + wc * 32 + ni * 16 + lr;
          C[row * (long)ldc + col] = f2b(__expf(acc[mi][ni][j] * alpha));
        }
  } else if constexpr (OUT_F32) {
    float* C = (float*)Cv + z * cStride;
#pragma unroll
    for (int mi = 0; mi < 4; ++mi)
#pragma unroll
      for (int ni = 0; ni < 2; ++ni)
#pragma unroll
        for (int j = 0; j < 4; ++j) {
          const long row = by + wr * 64 + mi * 16 + lg * 4 + j;
          const int col = bx + wc * 32 + ni * 16 + lr;
          float v = acc[mi][ni][j] * alpha;
          if (BIAS) v += bias[col];
          if (RES) v += res[row * (long)ldc + col];
          C[row * (long)ldc + col] = v;
        }
  } else {
    u16* C = (u16*)Cv + z * cStride;
#pragma unroll
    for (int mi = 0; mi < 4; ++mi)
#pragma unroll
      for (int j = 0; j < 4; ++j) {
        float invl = 1.0f;
        if constexpr (ROWSUM_DIV) invl = 1.0f / lsum[wr * 64 + mi * 16 + lg * 4 + j];
#pragma unroll
        for (int ni = 0; ni < 2; ++ni) {
          const long row = by + wr * 64 + mi * 16 + lg * 4 + j;
          const int col = bx + wc * 32 + ni * 16 + lr;
          float v = acc[mi][ni][j] * alpha;
          if constexpr (ROWSUM_DIV) v *= invl;
          if (BIAS) v += bias[col];
          C[row * (long)ldc + col] = f2b(v);
        }
      }
  }
}

extern "C" void kernel_launch(void* const* d_in, const int* in_sizes, int n_in,
                              void* d_out, int out_size, void* d_ws, size_t ws_size,
                              hipStream_t stream) {
  const float* x = (const float*)d_in[0];      // [8,2048,512]
  const float* w_qkv = (const float*)d_in[1];  // [512,1536]
  const float* b_qkv = (const float*)d_in[2];  // [1536]
  const float* w_fc = (const float*)d_in[3];   // [512,512]
  const float* b_fc = (const float*)d_in[4];   // [512]
  float* out = (float*)d_out;                  // [8,2048,512] f32

  char* ws = (char*)d_ws;
  const long MT = 16384;
  u16* xb = (u16*)(ws);                    // 16 MB  [16384][512]   (reused as attn_out)
  u16* wqkvT = (u16*)(ws + 16777216);      // 1.5 MB [1536][512]
  u16* wfcT = (u16*)(ws + 18350080);       // 0.5 MB [512][512]
  u16* qkv = (u16*)(ws + 18874368);        // 48 MB  [16384][1536]
  u16* vt = (u16*)(ws + 69206016);         // 16 MB  [8][512][2048]
  u16* S = (u16*)(ws + 85983232);          // 64 MB  [8][2048][2048]  (Pu)
  u16* attn = xb;

  cvt_f2b_kernel<<<4096, 256, 0, stream>>>(x, xb, MT * 512);
  tr_cvt<<<dim3(48, 16), 256, 0, stream>>>(w_qkv, wqkvT, 512, 1536);
  tr_cvt<<<dim3(16, 16), 256, 0, stream>>>(w_fc, wfcT, 512, 512);

  // qkv = x @ w_qkv + b_qkv   [16384 x 1536], K=512  (1536 blocks)
  gemm128t<false, true, false, false, false><<<dim3(12, 128, 1), 512, 0, stream>>>(
      xb, wqkvT, qkv, b_qkv, nullptr,
      512, 512, 512, 1536, 0, 0, 0, 1.0f);

  tr_v<<<dim3(64, 16, 8), 256, 0, stream>>>(qkv, vt);

  // Pu = exp(scale * Q @ K^T) per batch [2048 x 2048], K=512  (2048 blocks)
  gemm128t<false, false, false, true, false><<<dim3(16, 16, 8), 512, 0, stream>>>(
      qkv, qkv + 512, S, nullptr, nullptr,
      512, 1536, 1536, 2048,
      (long)2048 * 1536, (long)2048 * 1536, (long)2048 * 2048, 0.04419417382415922f);

  // attn = (Pu @ V) / l  per batch [2048 x 512], K=2048  (512 blocks)
  gemm128t<false, false, false, false, true><<<dim3(4, 16, 8), 512, 0, stream>>>(
      S, vt, attn, nullptr, nullptr,
      2048, 2048, 2048, 512,
      (long)2048 * 2048, (long)512 * 2048, (long)2048 * 512, 1.0f);

  // out = attn @ w_fc + b_fc + x  [16384 x 512], K=512  (512 blocks)
  gemm128t<true, true, true, false, false><<<dim3(4, 128, 1), 512, 0, stream>>>(
      attn, wfcT, out, b_fc, x,
      512, 512, 512, 512, 0, 0, 0, 1.0f);
}

// Round 15
// 163.459 us; speedup vs baseline: 1.0624x; 1.0624x over previous
//
#include <hip/hip_runtime.h>
#include <stdint.h>

typedef unsigned short u16;
typedef unsigned int u32;
typedef __attribute__((ext_vector_type(8))) short short8;
typedef __attribute__((ext_vector_type(4))) float f32x4;
typedef __attribute__((ext_vector_type(8))) unsigned short u16x8;
typedef __attribute__((ext_vector_type(4))) float float4_t;

__device__ __forceinline__ float b2f(u16 u) { return __uint_as_float(((u32)u) << 16); }
__device__ __forceinline__ u16 f2b(float f) {
  u32 u = __float_as_uint(f);
  u += 0x7fffu + ((u >> 16) & 1u);
  return (u16)(u >> 16);
}

typedef const __attribute__((address_space(1))) void* gas_t;
typedef __attribute__((address_space(3))) void* las_t;
__device__ __forceinline__ void gl_lds16(const void* g, void* l) {
  __builtin_amdgcn_global_load_lds((gas_t)(uintptr_t)g, (las_t)(u32)(uintptr_t)l, 16, 0, 0);
}
__device__ __forceinline__ void barrier_pin() {
  __builtin_amdgcn_sched_barrier(0);
  __builtin_amdgcn_s_barrier();
  __builtin_amdgcn_sched_barrier(0);
}
__device__ __forceinline__ void lgkm0_pin() {
  asm volatile("s_waitcnt lgkmcnt(0)" ::: "memory");
  __builtin_amdgcn_sched_barrier(0);  // rule #18: stop MFMA hoisting above the wait
}

// ---------------- fp32 -> bf16 convert (vectorized) ----------------
__global__ __launch_bounds__(256) void cvt_f2b_kernel(const float* __restrict__ src,
                                                      u16* __restrict__ dst, long n) {
  long i = ((long)blockIdx.x * 256 + threadIdx.x) * 8;
  if (i >= n) return;
  float4_t v0 = *(const float4_t*)(src + i);
  float4_t v1 = *(const float4_t*)(src + i + 4);
  u16x8 o;
#pragma unroll
  for (int j = 0; j < 4; ++j) { o[j] = f2b(v0[j]); o[4 + j] = f2b(v1[j]); }
  *(u16x8*)(dst + i) = o;
}

// ------------- fp32 [R][C] -> bf16 [C][R] transpose+convert (both weights) -------------
// z==0: w_qkv [512][1536]; z==1: w_fc [512][512] (blocks with bx>=16 exit).
__global__ __launch_bounds__(256) void tr_cvt2(const float* __restrict__ w1,
                                               u16* __restrict__ d1,
                                               const float* __restrict__ w2,
                                               u16* __restrict__ d2) {
  const int zz = blockIdx.z;
  if (zz == 1 && blockIdx.x >= 16) return;
  const float* src = zz ? w2 : w1;
  u16* dst = zz ? d2 : d1;
  const int C = zz ? 512 : 1536;
  const int R = 512;
  __shared__ float t[32][33];
  const int bx = blockIdx.x * 32;
  const int by = blockIdx.y * 32;
  const int tx = threadIdx.x & 31, ty = threadIdx.x >> 5;
#pragma unroll
  for (int i = 0; i < 32; i += 8)
    t[ty + i][tx] = src[(long)(by + ty + i) * C + bx + tx];
  __syncthreads();
#pragma unroll
  for (int i = 0; i < 32; i += 8)
    dst[(long)(bx + ty + i) * R + by + tx] = f2b(t[tx][ty + i]);
}

// ------------- V slice of qkv [B][N][1536] -> vt [B][512][2048] (bf16) -------------
__global__ __launch_bounds__(256) void tr_v(const u16* __restrict__ qkv, u16* __restrict__ vt) {
  __shared__ u16 t[32][33];
  const int b = blockIdx.z;
  const int r0 = blockIdx.x * 32;
  const int d0 = blockIdx.y * 32;
  const int tx = threadIdx.x & 31, ty = threadIdx.x >> 5;
#pragma unroll
  for (int i = 0; i < 32; i += 8)
    t[ty + i][tx] = qkv[((long)b * 2048 + r0 + ty + i) * 1536 + 1024 + d0 + tx];
  __syncthreads();
#pragma unroll
  for (int i = 0; i < 32; i += 8)
    vt[((long)b * 512 + d0 + ty + i) * 2048 + r0 + tx] = t[tx][ty + i];
}

// ======================= 128x128 2-phase BT-GEMM, 2 blocks/CU =======================
// THE ROUND-11 VERIFIED WINNER (163.6us config) — do not perturb the loop.
// C[M][N] = A[M][K] @ Bt[N][K]^T.  BM=BN=128, BK=64. 512 thr = 8 waves
// (wr=wid>>2: 64-row half; wc=wid&3: 32-col strip). Per-wave C = 64x32.
// LDS 2buf x (16+16) KB = 64 KB -> 2 blocks/CU.  Phase (T3 minimum-2-phase):
//   stage(T+1)->buf^1 ; ds_read tile T ; lgkm0 ; 16 MFMA ; vmcnt(0) ; BAR
// k-slot swizzle (both-sides, conflict-free b128) + XCD bijective remap.
// EXP_EPI (QK^T): p = exp2(alpha2*s), alpha2 = scale*log2(e) (v_exp_f32 is 2^x).
// ROWSUM_DIV (PV): l = rowsum(A) via gated ones-MFMA on wc==0 waves; O/l epilogue.
template <bool OUT_F32, bool BIAS, bool RES, bool EXP_EPI, bool ROWSUM_DIV>
__global__ __launch_bounds__(512, 4)
void gemm128(const u16* __restrict__ A, const u16* __restrict__ Bt, void* __restrict__ Cv,
             const float* __restrict__ bias, const float* __restrict__ res,
             int K, int lda, int ldb, int ldc,
             long aStride, long bStride, long cStride, float alpha) {
  __shared__ u16 As[2][128 * 64];
  __shared__ u16 Bs[2][128 * 64];
  __shared__ float lsum[ROWSUM_DIV ? 128 : 1];
  const int tid = threadIdx.x;
  const int wid = tid >> 6, lane = tid & 63;
  const int wr = wid >> 2, wc = wid & 3;
  const int lr = lane & 15, lg = lane >> 4;

  const int gx = gridDim.x, gy = gridDim.y;
  int id = (blockIdx.z * gy + blockIdx.y) * gx + blockIdx.x;
  const int nwg = gx * gy * gridDim.z;
  id = (id & 7) * (nwg >> 3) + (id >> 3);
  const int bxi = id % gx;
  const int t2 = id / gx;
  const int byi = t2 % gy;
  const long z = t2 / gy;

  A += z * aStride;
  Bt += z * bStride;
  const int by = byi * 128;
  const int bx = bxi * 128;

  f32x4 acc[4][2] = {};
  f32x4 acc_l[4] = {};  // row-sum accumulator (ROWSUM_DIV, wc==0 waves)
  short8 ah[4][2], bh[2][2];
  short8 ones;
#pragma unroll
  for (int j = 0; j < 8; ++j) ones[j] = (short)0x3F80;  // bf16 1.0

  const int w8l = wid * 8 + (lane >> 3);
  const int scol_src = ((lane & 7) ^ (lane >> 3)) * 8;  // pre-swizzled global slot
  const int scol_lin = (lane & 7) * 8;                  // linear LDS slot
  const int nT = K >> 6;
  const int sx = lane & 7;

  auto stage = [&](int kt) {
    const int bb = kt & 1;
    const long kc = (long)kt * 64 + scol_src;
#pragma unroll
    for (int r = 0; r < 2; ++r) {
      const int row = r * 64 + w8l;
      gl_lds16(A + (long)(by + row) * lda + kc, &As[bb][row * 64 + scol_lin]);
    }
#pragma unroll
    for (int r = 0; r < 2; ++r) {
      const int row = r * 64 + w8l;
      gl_lds16(Bt + (long)(bx + row) * ldb + kc, &Bs[bb][row * 64 + scol_lin]);
    }
  };

  // -------- prologue --------
  stage(0);
  asm volatile("s_waitcnt vmcnt(0)" ::: "memory");
  barrier_pin();

  // -------- main loop: one phase per K-tile --------
  for (int T = 0; T < nT; ++T) {
    const int bb = T & 1;
    const bool more = (T + 1) < nT;
    if (more) stage(T + 1);
#pragma unroll
    for (int mi = 0; mi < 4; ++mi)
#pragma unroll
      for (int ks = 0; ks < 2; ++ks)
        ah[mi][ks] = *(const short8*)&As[bb][(wr * 64 + mi * 16 + lr) * 64 +
                                             (((ks * 4 + lg) ^ sx) * 8)];
#pragma unroll
    for (int n = 0; n < 2; ++n)
#pragma unroll
      for (int ks = 0; ks < 2; ++ks)
        bh[n][ks] = *(const short8*)&Bs[bb][(wc * 32 + n * 16 + lr) * 64 +
                                            (((ks * 4 + lg) ^ sx) * 8)];
    lgkm0_pin();
    __builtin_amdgcn_s_setprio(1);
#pragma unroll
    for (int mi = 0; mi < 4; ++mi)
#pragma unroll
      for (int n = 0; n < 2; ++n)
#pragma unroll
        for (int ks = 0; ks < 2; ++ks)
          acc[mi][n] = __builtin_amdgcn_mfma_f32_16x16x32_bf16(
              ah[mi][ks], bh[n][ks], acc[mi][n], 0, 0, 0);
    if constexpr (ROWSUM_DIV) {
      if (wc == 0) {  // wave-uniform; A-frags identical across wc
#pragma unroll
        for (int mi = 0; mi < 4; ++mi)
#pragma unroll
          for (int ks = 0; ks < 2; ++ks)
            acc_l[mi] = __builtin_amdgcn_mfma_f32_16x16x32_bf16(
                ah[mi][ks], ones, acc_l[mi], 0, 0, 0);
      }
    }
    __builtin_amdgcn_s_setprio(0);
    if (more) asm volatile("s_waitcnt vmcnt(0)" ::: "memory");
    barrier_pin();
  }

  // -------- epilogue --------
  if constexpr (ROWSUM_DIV) {
    // every col of acc_l equals the row sum; rows lg*4+j match epilogue map
    if (wc == 0 && lr == 0) {
#pragma unroll
      for (int mi = 0; mi < 4; ++mi)
#pragma unroll
        for (int j = 0; j < 4; ++j)
          lsum[wr * 64 + mi * 16 + lg * 4 + j] = acc_l[mi][j];
    }
    __syncthreads();
  }

  if constexpr (EXP_EPI) {
    u16* C = (u16*)Cv + z * cStride;
#pragma unroll
    for (int mi = 0; mi < 4; ++mi)
#pragma unroll
      for (int ni = 0; ni < 2; ++ni)
#pragma unroll
        for (int j = 0; j < 4; ++j) {
          const long row = by + wr * 64 + mi * 16 + lg * 4 + j;
          const int col = bx + wc * 32 + ni * 16 + lr;
          C[row * (long)ldc + col] = f2b(exp2f(acc[mi][ni][j] * alpha));
        }
  } else if constexpr (OUT_F32) {
    float* C = (float*)Cv + z * cStride;
#pragma unroll
    for (int mi = 0; mi < 4; ++mi)
#pragma unroll
      for (int ni = 0; ni < 2; ++ni)
#pragma unroll
        for (int j = 0; j < 4; ++j) {
          const long row = by + wr * 64 + mi * 16 + lg * 4 + j;
          const int col = bx + wc * 32 + ni * 16 + lr;
          float v = acc[mi][ni][j] * alpha;
          if (BIAS) v += bias[col];
          if (RES) v += res[row * (long)ldc + col];
          C[row * (long)ldc + col] = v;
        }
  } else {
    u16* C = (u16*)Cv + z * cStride;
#pragma unroll
    for (int mi = 0; mi < 4; ++mi)
#pragma unroll
      for (int j = 0; j < 4; ++j) {
        float invl = 1.0f;
        if constexpr (ROWSUM_DIV) invl = 1.0f / lsum[wr * 64 + mi * 16 + lg * 4 + j];
#pragma unroll
        for (int ni = 0; ni < 2; ++ni) {
          const long row = by + wr * 64 + mi * 16 + lg * 4 + j;
          const int col = bx + wc * 32 + ni * 16 + lr;
          float v = acc[mi][ni][j] * alpha;
          if constexpr (ROWSUM_DIV) v *= invl;
          if (BIAS) v += bias[col];
          C[row * (long)ldc + col] = f2b(v);
        }
      }
  }
}

extern "C" void kernel_launch(void* const* d_in, const int* in_sizes, int n_in,
                              void* d_out, int out_size, void* d_ws, size_t ws_size,
                              hipStream_t stream) {
  const float* x = (const float*)d_in[0];      // [8,2048,512]
  const float* w_qkv = (const float*)d_in[1];  // [512,1536]
  const float* b_qkv = (const float*)d_in[2];  // [1536]
  const float* w_fc = (const float*)d_in[3];   // [512,512]
  const float* b_fc = (const float*)d_in[4];   // [512]
  float* out = (float*)d_out;                  // [8,2048,512] f32

  char* ws = (char*)d_ws;
  const long MT = 16384;
  u16* xb = (u16*)(ws);                    // 16 MB  [16384][512]   (reused as attn_out)
  u16* wqkvT = (u16*)(ws + 16777216);      // 1.5 MB [1536][512]
  u16* wfcT = (u16*)(ws + 18350080);       // 0.5 MB [512][512]
  u16* qkv = (u16*)(ws + 18874368);        // 48 MB  [16384][1536]
  u16* vt = (u16*)(ws + 69206016);         // 16 MB  [8][512][2048]
  u16* S = (u16*)(ws + 85983232);          // 64 MB  [8][2048][2048]  (Pu)
  u16* attn = xb;

  // scale * log2(e): exp(scale*s) == exp2(alpha2*s); v_exp_f32 computes 2^x
  const float alpha2 = 0.04419417382415922f * 1.4426950408889634f;

  cvt_f2b_kernel<<<4096, 256, 0, stream>>>(x, xb, MT * 512);
  tr_cvt2<<<dim3(48, 16, 2), 256, 0, stream>>>(w_qkv, wqkvT, w_fc, wfcT);

  // qkv = x @ w_qkv + b_qkv   [16384 x 1536], K=512
  gemm128<false, true, false, false, false><<<dim3(12, 128, 1), 512, 0, stream>>>(
      xb, wqkvT, qkv, b_qkv, nullptr,
      512, 512, 512, 1536, 0, 0, 0, 1.0f);

  tr_v<<<dim3(64, 16, 8), 256, 0, stream>>>(qkv, vt);

  // Pu = exp(scale * Q @ K^T) per batch [2048 x 2048], K=512
  gemm128<false, false, false, true, false><<<dim3(16, 16, 8), 512, 0, stream>>>(
      qkv, qkv + 512, S, nullptr, nullptr,
      512, 1536, 1536, 2048,
      (long)2048 * 1536, (long)2048 * 1536, (long)2048 * 2048, alpha2);

  // attn = (Pu @ V) / l  per batch [2048 x 512], K=2048 — l via gated ones-MFMA
  gemm128<false, false, false, false, true><<<dim3(4, 16, 8), 512, 0, stream>>>(
      S, vt, attn, nullptr, nullptr,
      2048, 2048, 2048, 512,
      (long)2048 * 2048, (long)512 * 2048, (long)2048 * 512, 1.0f);

  // out = attn @ w_fc + b_fc + x  [16384 x 512], K=512
  gemm128<true, true, true, false, false><<<dim3(4, 128, 1), 512, 0, stream>>>(
      attn, wfcT, out, b_fc, x,
      512, 512, 512, 512, 0, 0, 0, 1.0f);
}

// Round 16
// 160.311 us; speedup vs baseline: 1.0833x; 1.0196x over previous
//
#include <hip/hip_runtime.h>
#include <stdint.h>

typedef unsigned short u16;
typedef unsigned int u32;
typedef __attribute__((ext_vector_type(8))) short short8;
typedef __attribute__((ext_vector_type(4))) float f32x4;
typedef __attribute__((ext_vector_type(8))) unsigned short u16x8;
typedef __attribute__((ext_vector_type(4))) float float4_t;

__device__ __forceinline__ float b2f(u16 u) { return __uint_as_float(((u32)u) << 16); }
__device__ __forceinline__ u16 f2b(float f) {
  u32 u = __float_as_uint(f);
  u += 0x7fffu + ((u >> 16) & 1u);
  return (u16)(u >> 16);
}

typedef const __attribute__((address_space(1))) void* gas_t;
typedef __attribute__((address_space(3))) void* las_t;
__device__ __forceinline__ void gl_lds16(const void* g, void* l) {
  __builtin_amdgcn_global_load_lds((gas_t)(uintptr_t)g, (las_t)(u32)(uintptr_t)l, 16, 0, 0);
}
__device__ __forceinline__ void barrier_pin() {
  __builtin_amdgcn_sched_barrier(0);
  __builtin_amdgcn_s_barrier();
  __builtin_amdgcn_sched_barrier(0);
}
__device__ __forceinline__ void lgkm0_pin() {
  asm volatile("s_waitcnt lgkmcnt(0)" ::: "memory");
  __builtin_amdgcn_sched_barrier(0);  // rule #18: stop MFMA hoisting above the wait
}

// ---------------- fp32 -> bf16 convert (vectorized) ----------------
__global__ __launch_bounds__(256) void cvt_f2b_kernel(const float* __restrict__ src,
                                                      u16* __restrict__ dst, long n) {
  long i = ((long)blockIdx.x * 256 + threadIdx.x) * 8;
  if (i >= n) return;
  float4_t v0 = *(const float4_t*)(src + i);
  float4_t v1 = *(const float4_t*)(src + i + 4);
  u16x8 o;
#pragma unroll
  for (int j = 0; j < 4; ++j) { o[j] = f2b(v0[j]); o[4 + j] = f2b(v1[j]); }
  *(u16x8*)(dst + i) = o;
}

// ------------- fp32 [R][C] -> bf16 [C][R] transpose+convert (both weights) -------------
// z==0: w_qkv [512][1536]; z==1: w_fc [512][512] (blocks with bx>=16 exit).
__global__ __launch_bounds__(256) void tr_cvt2(const float* __restrict__ w1,
                                               u16* __restrict__ d1,
                                               const float* __restrict__ w2,
                                               u16* __restrict__ d2) {
  const int zz = blockIdx.z;
  if (zz == 1 && blockIdx.x >= 16) return;
  const float* src = zz ? w2 : w1;
  u16* dst = zz ? d2 : d1;
  const int C = zz ? 512 : 1536;
  const int R = 512;
  __shared__ float t[32][33];
  const int bx = blockIdx.x * 32;
  const int by = blockIdx.y * 32;
  const int tx = threadIdx.x & 31, ty = threadIdx.x >> 5;
#pragma unroll
  for (int i = 0; i < 32; i += 8)
    t[ty + i][tx] = src[(long)(by + ty + i) * C + bx + tx];
  __syncthreads();
#pragma unroll
  for (int i = 0; i < 32; i += 8)
    dst[(long)(bx + ty + i) * R + by + tx] = f2b(t[tx][ty + i]);
}

// ------------- V slice of qkv [B][N][1536] -> vt [B][512][2048] (bf16) -------------
// Vectorized: 64x64 tile, 512 thr, u16x8 (16B) loads/stores; LDS pad 66 to
// spread the transposed column reads across banks.
__global__ __launch_bounds__(512) void tr_v(const u16* __restrict__ qkv,
                                            u16* __restrict__ vt) {
  __shared__ u16 t[64][66];
  const int b = blockIdx.z;
  const int r0 = blockIdx.x * 64;  // token rows (2048/64 = 32)
  const int d0 = blockIdx.y * 64;  // feature (512/64 = 8)
  const int tr = threadIdx.x >> 3;        // 0..63
  const int tc = (threadIdx.x & 7) * 8;   // 0,8,..,56
  *(u16x8*)&t[tr][tc] =
      *(const u16x8*)&qkv[((long)b * 2048 + r0 + tr) * 1536 + 1024 + d0 + tc];
  __syncthreads();
  u16x8 o;
#pragma unroll
  for (int j = 0; j < 8; ++j) o[j] = t[tc + j][tr];
  *(u16x8*)&vt[((long)b * 512 + d0 + tr) * 2048 + r0 + tc] = o;
}

// ======================= 128x128 2-phase BT-GEMM, 2 blocks/CU =======================
// THE VERIFIED WINNER (r11/r15, 163.5us config) — hot loop unchanged.
// Phase: stage(T+1)->buf^1 ; ds_read tile T ; lgkm0 ; 16 MFMA ; vmcnt(0) ; BAR
// k-slot swizzle (both-sides, conflict-free b128) + XCD bijective remap.
// EXP_EPI (QK^T): p = exp2(alpha2*s).
// ROWSUM_ST (PV): l = rowsum(A) via gated ones-MFMA on wc==0 waves of the
//   bxi==0 col-blocks only (l identical across bxi); O_u stored UNNORMALIZED,
//   l -> lglob.  Normalization deferred through FC: (O_u/l)@W == (O_u@W)/l.
// DIVROW (FC): epilogue v = acc/l[row] + bias + res.
template <bool OUT_F32, bool BIAS, bool RES, bool EXP_EPI, bool ROWSUM_ST, bool DIVROW>
__global__ __launch_bounds__(512, 4)
void gemm128(const u16* __restrict__ A, const u16* __restrict__ Bt, void* __restrict__ Cv,
             const float* __restrict__ bias, const float* __restrict__ res,
             float* __restrict__ lglob, const float* __restrict__ lin,
             int K, int lda, int ldb, int ldc,
             long aStride, long bStride, long cStride, float alpha) {
  __shared__ u16 As[2][128 * 64];
  __shared__ u16 Bs[2][128 * 64];
  const int tid = threadIdx.x;
  const int wid = tid >> 6, lane = tid & 63;
  const int wr = wid >> 2, wc = wid & 3;
  const int lr = lane & 15, lg = lane >> 4;

  const int gx = gridDim.x, gy = gridDim.y;
  int id = (blockIdx.z * gy + blockIdx.y) * gx + blockIdx.x;
  const int nwg = gx * gy * gridDim.z;
  id = (id & 7) * (nwg >> 3) + (id >> 3);
  const int bxi = id % gx;
  const int t2 = id / gx;
  const int byi = t2 % gy;
  const long z = t2 / gy;

  A += z * aStride;
  Bt += z * bStride;
  const int by = byi * 128;
  const int bx = bxi * 128;

  const bool do_l = ROWSUM_ST && (bxi == 0);  // block-uniform

  f32x4 acc[4][2] = {};
  f32x4 acc_l[4] = {};  // row-sum accumulator (ROWSUM_ST, wc==0 waves, bxi==0)
  short8 ah[4][2], bh[2][2];
  short8 ones;
#pragma unroll
  for (int j = 0; j < 8; ++j) ones[j] = (short)0x3F80;  // bf16 1.0

  const int w8l = wid * 8 + (lane >> 3);
  const int scol_src = ((lane & 7) ^ (lane >> 3)) * 8;  // pre-swizzled global slot
  const int scol_lin = (lane & 7) * 8;                  // linear LDS slot
  const int nT = K >> 6;
  const int sx = lane & 7;

  auto stage = [&](int kt) {
    const int bb = kt & 1;
    const long kc = (long)kt * 64 + scol_src;
#pragma unroll
    for (int r = 0; r < 2; ++r) {
      const int row = r * 64 + w8l;
      gl_lds16(A + (long)(by + row) * lda + kc, &As[bb][row * 64 + scol_lin]);
    }
#pragma unroll
    for (int r = 0; r < 2; ++r) {
      const int row = r * 64 + w8l;
      gl_lds16(Bt + (long)(bx + row) * ldb + kc, &Bs[bb][row * 64 + scol_lin]);
    }
  };

  // -------- prologue --------
  stage(0);
  asm volatile("s_waitcnt vmcnt(0)" ::: "memory");
  barrier_pin();

  // -------- main loop: one phase per K-tile --------
  for (int T = 0; T < nT; ++T) {
    const int bb = T & 1;
    const bool more = (T + 1) < nT;
    if (more) stage(T + 1);
#pragma unroll
    for (int mi = 0; mi < 4; ++mi)
#pragma unroll
      for (int ks = 0; ks < 2; ++ks)
        ah[mi][ks] = *(const short8*)&As[bb][(wr * 64 + mi * 16 + lr) * 64 +
                                             (((ks * 4 + lg) ^ sx) * 8)];
#pragma unroll
    for (int n = 0; n < 2; ++n)
#pragma unroll
      for (int ks = 0; ks < 2; ++ks)
        bh[n][ks] = *(const short8*)&Bs[bb][(wc * 32 + n * 16 + lr) * 64 +
                                            (((ks * 4 + lg) ^ sx) * 8)];
    lgkm0_pin();
    __builtin_amdgcn_s_setprio(1);
#pragma unroll
    for (int mi = 0; mi < 4; ++mi)
#pragma unroll
      for (int n = 0; n < 2; ++n)
#pragma unroll
        for (int ks = 0; ks < 2; ++ks)
          acc[mi][n] = __builtin_amdgcn_mfma_f32_16x16x32_bf16(
              ah[mi][ks], bh[n][ks], acc[mi][n], 0, 0, 0);
    if constexpr (ROWSUM_ST) {
      if (do_l && wc == 0) {  // wave-uniform; A-frags identical across wc
#pragma unroll
        for (int mi = 0; mi < 4; ++mi)
#pragma unroll
          for (int ks = 0; ks < 2; ++ks)
            acc_l[mi] = __builtin_amdgcn_mfma_f32_16x16x32_bf16(
                ah[mi][ks], ones, acc_l[mi], 0, 0, 0);
      }
    }
    __builtin_amdgcn_s_setprio(0);
    if (more) asm volatile("s_waitcnt vmcnt(0)" ::: "memory");
    barrier_pin();
  }

  // -------- epilogue --------
  if constexpr (ROWSUM_ST) {
    // every col of acc_l equals the row sum; rows lg*4+j match epilogue map
    if (do_l && wc == 0 && lr == 0) {
#pragma unroll
      for (int mi = 0; mi < 4; ++mi)
#pragma unroll
        for (int j = 0; j < 4; ++j)
          lglob[z * 2048 + by + wr * 64 + mi * 16 + lg * 4 + j] = acc_l[mi][j];
    }
  }

  if constexpr (EXP_EPI) {
    u16* C = (u16*)Cv + z * cStride;
#pragma unroll
    for (int mi = 0; mi < 4; ++mi)
#pragma unroll
      for (int ni = 0; ni < 2; ++ni)
#pragma unroll
        for (int j = 0; j < 4; ++j) {
          const long row = by + wr * 64 + mi * 16 + lg * 4 + j;
          const int col = bx + wc * 32 + ni * 16 + lr;
          C[row * (long)ldc + col] = f2b(exp2f(acc[mi][ni][j] * alpha));
        }
  } else if constexpr (OUT_F32) {
    float* C = (float*)Cv + z * cStride;
#pragma unroll
    for (int mi = 0; mi < 4; ++mi)
#pragma unroll
      for (int j = 0; j < 4; ++j) {
        const long row = by + wr * 64 + mi * 16 + lg * 4 + j;
        float invl = 1.0f;
        if constexpr (DIVROW) invl = 1.0f / lin[row];
#pragma unroll
        for (int ni = 0; ni < 2; ++ni) {
          const int col = bx + wc * 32 + ni * 16 + lr;
          float v = acc[mi][ni][j] * alpha;
          if constexpr (DIVROW) v = acc[mi][ni][j] * invl;
          if (BIAS) v += bias[col];
          if (RES) v += res[row * (long)ldc + col];
          C[row * (long)ldc + col] = v;
        }
      }
  } else {
    u16* C = (u16*)Cv + z * cStride;
#pragma unroll
    for (int mi = 0; mi < 4; ++mi)
#pragma unroll
      for (int ni = 0; ni < 2; ++ni)
#pragma unroll
        for (int j = 0; j < 4; ++j) {
          const long row = by + wr * 64 + mi * 16 + lg * 4 + j;
          const int col = bx + wc * 32 + ni * 16 + lr;
          float v = acc[mi][ni][j] * alpha;
          if (BIAS) v += bias[col];
          C[row * (long)ldc + col] = f2b(v);
        }
  }
}

extern "C" void kernel_launch(void* const* d_in, const int* in_sizes, int n_in,
                              void* d_out, int out_size, void* d_ws, size_t ws_size,
                              hipStream_t stream) {
  const float* x = (const float*)d_in[0];      // [8,2048,512]
  const float* w_qkv = (const float*)d_in[1];  // [512,1536]
  const float* b_qkv = (const float*)d_in[2];  // [1536]
  const float* w_fc = (const float*)d_in[3];   // [512,512]
  const float* b_fc = (const float*)d_in[4];   // [512]
  float* out = (float*)d_out;                  // [8,2048,512] f32

  char* ws = (char*)d_ws;
  const long MT = 16384;
  u16* xb = (u16*)(ws);                    // 16 MB  [16384][512]   (reused as attn_out)
  u16* wqkvT = (u16*)(ws + 16777216);      // 1.5 MB [1536][512] (dead after QKV ->
                                           //        l overlays it, r9-proven pattern)
  u16* wfcT = (u16*)(ws + 18350080);       // 0.5 MB [512][512]
  u16* qkv = (u16*)(ws + 18874368);        // 48 MB  [16384][1536]
  u16* vt = (u16*)(ws + 69206016);         // 16 MB  [8][512][2048]
  u16* S = (u16*)(ws + 85983232);          // 64 MB  [8][2048][2048]  (Pu)
  u16* attn = xb;                          // raw O_u (unnormalized)
  float* lvec = (float*)(ws + 16777216);   // 64 KB [16384] row sums (overlays wqkvT)

  // scale * log2(e): exp(scale*s) == exp2(alpha2*s); v_exp_f32 computes 2^x
  const float alpha2 = 0.04419417382415922f * 1.4426950408889634f;

  cvt_f2b_kernel<<<4096, 256, 0, stream>>>(x, xb, MT * 512);
  tr_cvt2<<<dim3(48, 16, 2), 256, 0, stream>>>(w_qkv, wqkvT, w_fc, wfcT);

  // qkv = x @ w_qkv + b_qkv   [16384 x 1536], K=512
  gemm128<false, true, false, false, false, false><<<dim3(12, 128, 1), 512, 0, stream>>>(
      xb, wqkvT, qkv, b_qkv, nullptr, nullptr, nullptr,
      512, 512, 512, 1536, 0, 0, 0, 1.0f);

  tr_v<<<dim3(32, 8, 8), 512, 0, stream>>>(qkv, vt);

  // Pu = exp(scale * Q @ K^T) per batch [2048 x 2048], K=512
  gemm128<false, false, false, true, false, false><<<dim3(16, 16, 8), 512, 0, stream>>>(
      qkv, qkv + 512, S, nullptr, nullptr, nullptr, nullptr,
      512, 1536, 1536, 2048,
      (long)2048 * 1536, (long)2048 * 1536, (long)2048 * 2048, alpha2);

  // O_u = Pu @ V (unnormalized) per batch [2048 x 512], K=2048; l -> lvec
  gemm128<false, false, false, false, true, false><<<dim3(4, 16, 8), 512, 0, stream>>>(
      S, vt, attn, nullptr, nullptr, lvec, nullptr,
      2048, 2048, 2048, 512,
      (long)2048 * 2048, (long)512 * 2048, (long)2048 * 512, 1.0f);

  // out = (O_u @ w_fc)/l + b_fc + x  [16384 x 512], K=512
  gemm128<true, true, true, false, false, true><<<dim3(4, 128, 1), 512, 0, stream>>>(
      attn, wfcT, out, b_fc, x, nullptr, lvec,
      512, 512, 512, 512, 0, 0, 0, 1.0f);
}